// Round 12
// baseline (1467.046 us; speedup 1.0000x reference)
//
#include <hip/hip_runtime.h>

#define BATCH  4096
#define TSTEPS 64
#define FDIM   128
#define HDIM   256
#define ODIM   64
#define MROWS  32
#define NBLK   128    // BATCH / MROWS
#define NTHR   1024   // 16 waves, 1 block/CU (160KB LDS), 4 waves/SIMD

#define SMEM_BYTES 163840   // sm_h 16K + ring 144K (16 waves x 3 slots x 3KB)

typedef __attribute__((ext_vector_type(8))) short  short8;
typedef __attribute__((ext_vector_type(4))) float  floatx4;

#define MFMA(a,b,c) __builtin_amdgcn_mfma_f32_16x16x32_bf16((a),(b),(c),0,0,0)

__device__ __forceinline__ unsigned short f2bf(float f){
  unsigned u = __builtin_bit_cast(unsigned, f);
  u += 0x7FFFu + ((u >> 16) & 1u);           // RTNE
  return (unsigned short)(u >> 16);
}
__device__ __forceinline__ float sigm(float x){
  return __builtin_amdgcn_rcpf(1.f + __expf(-x));
}
__device__ __forceinline__ float tanh_f(float x){
  return 2.f * __builtin_amdgcn_rcpf(1.f + __expf(-2.f * x)) - 1.f;
}

// async 16B/lane global -> LDS (LDS dest = wave-uniform base + lane*16)
__device__ __forceinline__ void dma16(const void* g, void* l){
  __builtin_amdgcn_global_load_lds(
      (const __attribute__((address_space(1))) unsigned int*)g,
      (__attribute__((address_space(3))) unsigned int*)l, 16, 0, 0);
}

// ---------------- phase 0: fragment weights into d_ws ----------
// warr[((gf*12 + kf)*64 + lane)*8 + i]; gf 0..47, kf 0..7 = w_hh, 8..11 = w_ih
// element = W[16*gf + (lane&15)][32*kf + 8*(lane>>4) + i]  (A-frag, row=lane&15)
__global__ void prep_weights(const float* __restrict__ w_ih,
                             const float* __restrict__ w_hh,
                             unsigned short* __restrict__ warr){
  int idx = blockIdx.x * 256 + threadIdx.x;
  if (idx >= 48*12*64) return;
  int gf   = idx / 768;
  int rr   = idx - gf*768;
  int kf   = rr >> 6;
  int lane = rr & 63;
  int lo = lane & 15, hi = lane >> 4;
  const float* src = (kf < 8) ? (w_hh + (size_t)(16*gf + lo)*HDIM + 32*kf     + 8*hi)
                              : (w_ih + (size_t)(16*gf + lo)*FDIM + 32*(kf-8) + 8*hi);
  unsigned short* dst = warr + (size_t)idx * 8;
  #pragma unroll
  for (int i = 0; i < 8; ++i) dst[i] = f2bf(src[i]);
}

// ---- LDS swizzle (bank-quad = (col>>4) ^ (row&7); conflict-minimal)
__device__ __forceinline__ short8 ldsH(const unsigned char* sm, int row, int col){
  return *(const short8*)(sm + row*512 + (col ^ ((row & 7) << 4)));
}

__device__ __forceinline__ short8 cvt8(floatx4 a, floatx4 b){
  union { unsigned u[4]; short8 s; } r;
  r.u[0] = (unsigned)f2bf(a[0]) | ((unsigned)f2bf(a[1]) << 16);
  r.u[1] = (unsigned)f2bf(a[2]) | ((unsigned)f2bf(a[3]) << 16);
  r.u[2] = (unsigned)f2bf(b[0]) | ((unsigned)f2bf(b[1]) << 16);
  r.u[3] = (unsigned)f2bf(b[2]) | ((unsigned)f2bf(b[3]) << 16);
  return r.s;
}

// DMA the 3 A-frags for round index I (0..13; 12,13 = next step r0,r1)
#define DMAI(I) { \
    constexpr int mm_ = (I) % 12; \
    constexpr int kf_ = (mm_ < 8) ? ((mm_ + KOFF) & 7) : mm_; \
    unsigned char* dst_ = ring_w + ((I) % 3) * 3072; \
    dma16(wsrc + (size_t)((     wv)*12 + kf_)*1024, dst_); \
    dma16(wsrc + (size_t)((16 + wv)*12 + kf_)*1024, dst_ + 1024); \
    dma16(wsrc + (size_t)((32 + wv)*12 + kf_)*1024, dst_ + 2048); }

// asm x-loads for x-round kx (B-frags rows lo / 16+lo), 4 dwordx4, untracked
#define XLDA(KX, A0, A1, A2, A3) { \
    const float* p0_ = xbase + 32*(KX); \
    const float* p1_ = p0_ + (size_t)16*(TSTEPS*FDIM); \
    asm volatile("global_load_dwordx4 %0, %2, off\n\t" \
                 "global_load_dwordx4 %1, %2, off offset:16" \
                 : "=&v"(A0), "=&v"(A1) : "v"(p0_) : "memory"); \
    asm volatile("global_load_dwordx4 %0, %2, off\n\t" \
                 "global_load_dwordx4 %1, %2, off offset:16" \
                 : "=&v"(A2), "=&v"(A3) : "v"(p1_) : "memory"); }

#define WAITV(N) asm volatile("s_waitcnt vmcnt(" #N ")" ::: "memory");
#define WAITL0   asm volatile("s_waitcnt lgkmcnt(0)" ::: "memory");

// h-round G (0..7): A from ring, B from sm_h
#define RNDH(G, WN) { \
    WAITL0                      /* ring reads of G-1 done -> slot (G+2)%3 free */ \
    DMAI((G)+2) \
    WAITV(WN)                   /* slot G data landed */ \
    constexpr int kf_ = ((G) + KOFF) & 7; \
    short8 b0 = ldsH(sm_h, lo,      kf_*64 + hi*16); \
    short8 b1 = ldsH(sm_h, 16 + lo, kf_*64 + hi*16); \
    const unsigned char* rs_ = ring_r + ((G) % 3) * 3072; \
    short8 a0 = *(const short8*)(rs_); \
    short8 a1 = *(const short8*)(rs_ + 1024); \
    short8 a2 = *(const short8*)(rs_ + 2048); \
    ar[0] = MFMA(a0, b0, ar[0]); ar[1] = MFMA(a0, b1, ar[1]); \
    az[0] = MFMA(a1, b0, az[0]); az[1] = MFMA(a1, b1, az[1]); \
    anh[0] = MFMA(a2, b0, anh[0]); anh[1] = MFMA(a2, b1, anh[1]); }

// x-round G (8..11): A from ring, B from asm-loaded regs (set X0..X3)
#define RNDX(G, WN, X0, X1, X2, X3) { \
    WAITV(WN) \
    __builtin_amdgcn_sched_barrier(0);   /* X regs are asm-loaded: pin */ \
    short8 b0 = cvt8(X0, X1); \
    short8 b1 = cvt8(X2, X3); \
    const unsigned char* rs_ = ring_r + ((G) % 3) * 3072; \
    short8 a0 = *(const short8*)(rs_); \
    short8 a1 = *(const short8*)(rs_ + 1024); \
    short8 a2 = *(const short8*)(rs_ + 2048); \
    ar[0] = MFMA(a0, b0, ar[0]); ar[1] = MFMA(a0, b1, ar[1]); \
    az[0] = MFMA(a1, b0, az[0]); az[1] = MFMA(a1, b1, az[1]); \
    anx[0] = MFMA(a2, b0, anx[0]); anx[1] = MFMA(a2, b1, anx[1]); }

// ---------------- main fused kernel ----------------
template<int KOFF>
__device__ __forceinline__ void gru_body(
    const float* __restrict__ feat, const unsigned short* __restrict__ warr,
    const float* __restrict__ b_ih, const float* __restrict__ b_hh,
    const float* __restrict__ w_pi, const float* __restrict__ b_pi,
    const float* __restrict__ w_vf, const float* __restrict__ b_vf,
    float* __restrict__ out, unsigned char* smem){

  const int tid  = threadIdx.x;
  const int wv   = tid >> 6;              // 0..15 -> gate-col frags wv, 16+wv, 32+wv
  const int lane = tid & 63;
  const int lo   = lane & 15, hi = lane >> 4;
  const int row0 = blockIdx.x * MROWS;
  const int cb   = 16*wv + 4*hi;          // gate/h col base for this lane

  unsigned char* sm_h  = smem;                          // 16 KB [32][256] bf16 swizzled
  unsigned char* ring  = smem + 16384 + wv*9216;        // 3 slots x 3 KB per wave
  const unsigned char* ring_r = ring + lane*16;
  unsigned char*       ring_w = ring;                   // uniform; HW adds lane*16
  const unsigned char* wsrc   = (const unsigned char*)warr + lane*16;

  // ---- bias -> registers (one-time; no tracked vmem inside the t-loop)
  floatx4 vr = *(const floatx4*)(b_ih + cb)       + *(const floatx4*)(b_hh + cb);
  floatx4 vz = *(const floatx4*)(b_ih + 256 + cb) + *(const floatx4*)(b_hh + 256 + cb);
  floatx4 vx = *(const floatx4*)(b_ih + 512 + cb);
  floatx4 vh = *(const floatx4*)(b_hh + 512 + cb);

  // ---- zero sm_h
  ((int4*)sm_h)[tid] = make_int4(0,0,0,0);

  float hold[2][4] = {};

  __syncthreads();     // full drain OK (before any ring DMAs)

  DMAI(0) DMAI(1)      // prologue: 6 DMAs in flight

  #pragma unroll 1
  for (int t = 0; t < TSTEPS; ++t){
    const float* xbase = feat + (size_t)(row0 + lo)*(TSTEPS*FDIM) + (size_t)t*FDIM + 8*hi;
    floatx4 ar[2], az[2], anh[2], anx[2];
    ar[0]=vr; ar[1]=vr; az[0]=vz; az[1]=vz;
    anh[0]=vh; anh[1]=vh; anx[0]=vx; anx[1]=vx;
    floatx4 xa0, xa1, xa2, xa3, xb0, xb1, xb2, xb3;

    RNDH(0,6) RNDH(1,6) RNDH(2,6) RNDH(3,6) RNDH(4,6) RNDH(5,6) RNDH(6,6)
    // r7: also issue x-loads for r8 (set A) after the DMA
    { WAITL0 DMAI(9) XLDA(0, xa0, xa1, xa2, xa3)
      WAITV(10)
      constexpr int kf_ = (7 + KOFF) & 7;
      short8 b0 = ldsH(sm_h, lo,      kf_*64 + hi*16);
      short8 b1 = ldsH(sm_h, 16 + lo, kf_*64 + hi*16);
      const unsigned char* rs_ = ring_r + (7 % 3) * 3072;
      short8 a0 = *(const short8*)(rs_);
      short8 a1 = *(const short8*)(rs_ + 1024);
      short8 a2 = *(const short8*)(rs_ + 2048);
      ar[0] = MFMA(a0, b0, ar[0]); ar[1] = MFMA(a0, b1, ar[1]);
      az[0] = MFMA(a1, b0, az[0]); az[1] = MFMA(a1, b1, az[1]);
      anh[0] = MFMA(a2, b0, anh[0]); anh[1] = MFMA(a2, b1, anh[1]); }

    // r8: top issues DMA(10) + XLD_9 (set B); consume set A. wait 7
    WAITL0 DMAI(10) XLDA(1, xb0, xb1, xb2, xb3)
    RNDX(8, 7, xa0, xa1, xa2, xa3)
    // r9: top issues DMA(11) + XLD_10 (set A); consume set B. wait 7
    WAITL0 DMAI(11) XLDA(2, xa0, xa1, xa2, xa3)
    RNDX(9, 7, xb0, xb1, xb2, xb3)
    // r10: top issues XLD_11 (set B) FIRST, then DMA(12=nr0); consume set A. wait 7
    WAITL0 XLDA(3, xb0, xb1, xb2, xb3) DMAI(12)
    RNDX(10, 7, xa0, xa1, xa2, xa3)
    // r11: top issues DMA(13=nr1); consume set B. wait 6
    WAITL0 DMAI(13)
    RNDX(11, 6, xb0, xb1, xb2, xb3)

    __builtin_amdgcn_s_barrier();   // all sm_h reads done; 6 DMAs stay in flight

    // ---- lane-local gate math; write h_new (bf16, swizzled, 8B packed)
    #pragma unroll
    for (int m = 0; m < 2; ++m){
      int row = 16*m + lo;
      unsigned q[4];
      #pragma unroll
      for (int j = 0; j < 4; ++j){
        float r  = sigm(ar[m][j]);
        float z  = sigm(az[m][j]);
        float n  = tanh_f(anx[m][j] + r*anh[m][j]);
        float hv = (1.f - z)*n + z*hold[m][j];
        hold[m][j] = hv;
        q[j] = f2bf(hv);
      }
      uint2 pk; pk.x = q[0] | (q[1] << 16); pk.y = q[2] | (q[3] << 16);
      *(uint2*)(sm_h + row*512 + ((cb*2) ^ ((row & 7) << 4))) = pk;
    }
    WAITL0
    __builtin_amdgcn_s_barrier();   // h[t+1] visible; ring DMAs still in flight
  }

  WAITV(0)   // drain tail DMAs

  // ---- epilogue: leaky(h_last) -> sm_h (bf16)
  #pragma unroll
  for (int m = 0; m < 2; ++m){
    int row = 16*m + lo;
    unsigned q[4];
    #pragma unroll
    for (int j = 0; j < 4; ++j){
      float v = hold[m][j];
      v = (v >= 0.f) ? v : 0.01f*v;
      q[j] = f2bf(v);
    }
    uint2 pk; pk.x = q[0] | (q[1] << 16); pk.y = q[2] | (q[3] << 16);
    *(uint2*)(sm_h + row*512 + ((cb*2) ^ ((row & 7) << 4))) = pk;
  }
  WAITL0
  __builtin_amdgcn_s_barrier();

  // ---- heads: 16 waves = 2 heads x 4 out-frags x 2 row-frags
  const int head = wv >> 3;
  const int mfo  = (wv >> 1) & 3;
  const int rh   = wv & 1;
  const float* wh = head ? w_vf : w_pi;
  const float* bh = head ? b_vf : b_pi;
  floatx4 acc = {0.f,0.f,0.f,0.f};
  #pragma unroll
  for (int kf = 0; kf < 8; ++kf){
    const float* ap = wh + (size_t)(16*mfo + lo)*HDIM + 32*kf + 8*hi;
    floatx4 av0 = *(const floatx4*)ap;
    floatx4 av1 = *(const floatx4*)(ap + 4);
    short8 a;
    a[0]=(short)f2bf(av0[0]); a[1]=(short)f2bf(av0[1]); a[2]=(short)f2bf(av0[2]); a[3]=(short)f2bf(av0[3]);
    a[4]=(short)f2bf(av1[0]); a[5]=(short)f2bf(av1[1]); a[6]=(short)f2bf(av1[2]); a[7]=(short)f2bf(av1[3]);
    short8 b = ldsH(sm_h, 16*rh + lo, kf*64 + hi*16);
    acc = MFMA(a, b, acc);
  }
  const size_t outoff = (size_t)head * ((size_t)BATCH * ODIM);
  {
    int grow = row0 + 16*rh + lo;
    #pragma unroll
    for (int j = 0; j < 4; ++j){
      int od = 16*mfo + 4*hi + j;
      float v = acc[j] + bh[od];
      v = (v >= 0.f) ? v : 0.01f*v;
      out[outoff + (size_t)grow*ODIM + od] = v;
    }
  }
}

__global__ __launch_bounds__(NTHR, 4)
void gru_fused(const float* __restrict__ feat, const unsigned short* __restrict__ warr,
               const float* __restrict__ b_ih, const float* __restrict__ b_hh,
               const float* __restrict__ w_pi, const float* __restrict__ b_pi,
               const float* __restrict__ w_vf, const float* __restrict__ b_vf,
               float* __restrict__ out){
  extern __shared__ __align__(16) unsigned char smem[];
  if (blockIdx.x & 1)
    gru_body<4>(feat, warr, b_ih, b_hh, w_pi, b_pi, w_vf, b_vf, out, smem);
  else
    gru_body<0>(feat, warr, b_ih, b_hh, w_pi, b_pi, w_vf, b_vf, out, smem);
}

extern "C" void kernel_launch(void* const* d_in, const int* in_sizes, int n_in,
                              void* d_out, int out_size, void* d_ws, size_t ws_size,
                              hipStream_t stream){
  const float* feat = (const float*)d_in[0];
  const float* w_ih = (const float*)d_in[1];
  const float* w_hh = (const float*)d_in[2];
  const float* b_ih = (const float*)d_in[3];
  const float* b_hh = (const float*)d_in[4];
  const float* w_pi = (const float*)d_in[5];
  const float* b_pi = (const float*)d_in[6];
  const float* w_vf = (const float*)d_in[7];
  const float* b_vf = (const float*)d_in[8];

  unsigned short* warr = (unsigned short*)d_ws;   // 589824 B

  hipFuncSetAttribute((const void*)gru_fused,
                      hipFuncAttributeMaxDynamicSharedMemorySize, SMEM_BYTES);

  prep_weights<<<144, 256, 0, stream>>>(w_ih, w_hh, warr);
  gru_fused<<<NBLK, NTHR, SMEM_BYTES, stream>>>(feat, warr, b_ih, b_hh,
                                                w_pi, b_pi, w_vf, b_vf, (float*)d_out);
}

// Round 13
// 944.801 us; speedup vs baseline: 1.5528x; 1.5528x over previous
//
#include <hip/hip_runtime.h>

#define BATCH  4096
#define TSTEPS 64
#define FDIM   128
#define HDIM   256
#define ODIM   64
#define MROWS  32
#define NBLK   128    // BATCH / MROWS
#define NTHR   512    // 8 waves, 2 waves/SIMD -> 256-reg/wave budget

typedef __attribute__((ext_vector_type(8))) short  short8;
typedef __attribute__((ext_vector_type(4))) float  floatx4;

#define MFMA(a,b,c) __builtin_amdgcn_mfma_f32_16x16x32_bf16((a),(b),(c),0,0,0)

__device__ __forceinline__ unsigned short f2bf(float f){
  unsigned u = __builtin_bit_cast(unsigned, f);
  u += 0x7FFFu + ((u >> 16) & 1u);           // RTNE
  return (unsigned short)(u >> 16);
}
__device__ __forceinline__ float sigm(float x){
  return __builtin_amdgcn_rcpf(1.f + __expf(-x));
}
__device__ __forceinline__ float tanh_f(float x){
  return 2.f * __builtin_amdgcn_rcpf(1.f + __expf(-2.f * x)) - 1.f;
}

// ---------------- phase 0: fragment weights into d_ws ----------
// warr[((gf*12 + kf)*64 + lane)*8 + i]; gf 0..47, kf 0..7 = w_hh, 8..11 = w_ih
// element = W[16*gf + (lane&15)][32*kf + 8*(lane>>4) + i]  (A-frag, row=lane&15)
__global__ void prep_weights(const float* __restrict__ w_ih,
                             const float* __restrict__ w_hh,
                             unsigned short* __restrict__ warr){
  int idx = blockIdx.x * 256 + threadIdx.x;
  if (idx >= 48*12*64) return;
  int gf   = idx / 768;
  int rr   = idx - gf*768;
  int kf   = rr >> 6;
  int lane = rr & 63;
  int lo = lane & 15, hi = lane >> 4;
  const float* src = (kf < 8) ? (w_hh + (size_t)(16*gf + lo)*HDIM + 32*kf     + 8*hi)
                              : (w_ih + (size_t)(16*gf + lo)*FDIM + 32*(kf-8) + 8*hi);
  unsigned short* dst = warr + (size_t)idx * 8;
  #pragma unroll
  for (int i = 0; i < 8; ++i) dst[i] = f2bf(src[i]);
}

// ---- LDS swizzle (bank-quad = (col>>4) ^ (row&7); conflict-minimal)
__device__ __forceinline__ short8 ldsH(const unsigned char* sm, int row, int col){
  return *(const short8*)(sm + row*512 + (col ^ ((row & 7) << 4)));
}
__device__ __forceinline__ short8 ldsX(const unsigned char* sm, int row, int col){
  return *(const short8*)(sm + row*256 + (col ^ ((row & 7) << 4)));
}

// load stage S with k-frag KF: this wave's 6 gate-col frags (r0,r1,z0,z1,n0,n1)
#define LOADSTG(S, KF) \
    sa##S##_0 = *(const short8*)(wl + ((2*wv+0)*12      + (KF))*512); \
    sa##S##_1 = *(const short8*)(wl + ((2*wv+1)*12      + (KF))*512); \
    sa##S##_2 = *(const short8*)(wl + ((16+2*wv+0)*12   + (KF))*512); \
    sa##S##_3 = *(const short8*)(wl + ((16+2*wv+1)*12   + (KF))*512); \
    sa##S##_4 = *(const short8*)(wl + ((32+2*wv+0)*12   + (KF))*512); \
    sa##S##_5 = *(const short8*)(wl + ((32+2*wv+1)*12   + (KF))*512);

// round G consuming stage S (= G%4); reload stage with kf = G+4 under the MFMAs
#define RND(G, S) { \
    short8 b0, b1; \
    if constexpr ((G) < 8){ \
      b0 = ldsH(sm_h, lo,      (G)*64 + hi*16); \
      b1 = ldsH(sm_h, 16 + lo, (G)*64 + hi*16); \
    } else { \
      b0 = ldsX(sm_x, lo,      ((G)-8)*64 + hi*16); \
      b1 = ldsX(sm_x, 16 + lo, ((G)-8)*64 + hi*16); \
    } \
    ar[0][0] = MFMA(sa##S##_0, b0, ar[0][0]); ar[0][1] = MFMA(sa##S##_0, b1, ar[0][1]); \
    ar[1][0] = MFMA(sa##S##_1, b0, ar[1][0]); ar[1][1] = MFMA(sa##S##_1, b1, ar[1][1]); \
    az[0][0] = MFMA(sa##S##_2, b0, az[0][0]); az[0][1] = MFMA(sa##S##_2, b1, az[0][1]); \
    az[1][0] = MFMA(sa##S##_3, b0, az[1][0]); az[1][1] = MFMA(sa##S##_3, b1, az[1][1]); \
    if constexpr ((G) < 8){ \
      anh[0][0] = MFMA(sa##S##_4, b0, anh[0][0]); anh[0][1] = MFMA(sa##S##_4, b1, anh[0][1]); \
      anh[1][0] = MFMA(sa##S##_5, b0, anh[1][0]); anh[1][1] = MFMA(sa##S##_5, b1, anh[1][1]); \
    } else { \
      anx[0][0] = MFMA(sa##S##_4, b0, anx[0][0]); anx[0][1] = MFMA(sa##S##_4, b1, anx[0][1]); \
      anx[1][0] = MFMA(sa##S##_5, b0, anx[1][0]); anx[1][1] = MFMA(sa##S##_5, b1, anx[1][1]); \
    } \
    if constexpr ((G) + 4 < 12){ LOADSTG(S, (G)+4) } \
  }

// ---------------- main fused kernel ----------------
__global__ __launch_bounds__(NTHR, 2)
void gru_fused(const float* __restrict__ feat, const unsigned short* __restrict__ warr,
               const float* __restrict__ b_ih, const float* __restrict__ b_hh,
               const float* __restrict__ w_pi, const float* __restrict__ b_pi,
               const float* __restrict__ w_vf, const float* __restrict__ b_vf,
               float* __restrict__ out){
  __shared__ __align__(16) unsigned char sm_h[MROWS*512];   // 16 KB bf16 [32][256] swizzled
  __shared__ __align__(16) unsigned char sm_x[MROWS*256];   // 8 KB  bf16 [32][128] swizzled

  const int tid  = threadIdx.x;
  const int wv   = tid >> 6;              // 0..7 -> owns h-cols [32wv, 32wv+32)
  const int lane = tid & 63;
  const int lo   = lane & 15, hi = lane >> 4;
  const int row0 = blockIdx.x * MROWS;

  const unsigned short* wl = warr + lane*8;

  // ---- bias -> registers, once (loop-invariant): per cf (2 h-col frags)
  floatx4 vr[2], vz[2], vx[2], vh[2];
  #pragma unroll
  for (int cf = 0; cf < 2; ++cf){
    int cbf = 32*wv + 16*cf + 4*hi;
    vr[cf] = *(const floatx4*)(b_ih + cbf)       + *(const floatx4*)(b_hh + cbf);
    vz[cf] = *(const floatx4*)(b_ih + 256 + cbf) + *(const floatx4*)(b_hh + 256 + cbf);
    vx[cf] = *(const floatx4*)(b_ih + 512 + cbf);
    vh[cf] = *(const floatx4*)(b_hh + 512 + cbf);
  }

  // ---- zero sm_h (1024 int4, 2/thread); stage x[0] (1024 float4-chunks, 2/thread)
  #pragma unroll
  for (int i = 0; i < 2; ++i) ((int4*)sm_h)[tid + i*NTHR] = make_int4(0,0,0,0);
  #pragma unroll
  for (int i = 0; i < 2; ++i){
    int cid = tid + i*NTHR;
    int r   = cid >> 5;
    int c4  = cid & 31;
    floatx4 v = __builtin_nontemporal_load(
        (const floatx4*)(feat + (size_t)(row0 + r)*(TSTEPS*FDIM)) + c4);
    uint2 pk;
    pk.x = (unsigned)f2bf(v[0]) | ((unsigned)f2bf(v[1]) << 16);
    pk.y = (unsigned)f2bf(v[2]) | ((unsigned)f2bf(v[3]) << 16);
    *(uint2*)(sm_x + r*256 + ((c4*8) ^ ((r & 7) << 4))) = pk;
  }

  float hold[2][2][4] = {};    // [cf][rf][j]

  __syncthreads();

  const int xr  = tid >> 5;    // x-staging coords (2 chunks/thread)
  const int xc4 = tid & 31;

  #pragma unroll 1
  for (int t = 0; t < TSTEPS; ++t){
    // ---- prefetch x[t+1] (nontemporal; written after the mid barrier)
    int tn = (t < TSTEPS-1) ? (t+1) : (TSTEPS-1);
    floatx4 xf0 = __builtin_nontemporal_load(
        (const floatx4*)(feat + (size_t)(row0 + xr)*(TSTEPS*FDIM) + (size_t)tn*FDIM) + xc4);
    floatx4 xf1 = __builtin_nontemporal_load(
        (const floatx4*)(feat + (size_t)(row0 + 16 + xr)*(TSTEPS*FDIM) + (size_t)tn*FDIM) + xc4);

    // ---- acc init from bias registers
    floatx4 ar[2][2], az[2][2], anh[2][2], anx[2][2];
    #pragma unroll
    for (int cf = 0; cf < 2; ++cf)
      #pragma unroll
      for (int rf = 0; rf < 2; ++rf){
        ar[cf][rf] = vr[cf]; az[cf][rf]  = vz[cf];
        anh[cf][rf] = vh[cf]; anx[cf][rf] = vx[cf];
      }

    // ---- depth-4 A pipeline: fill 4 stages (24 loads in flight), then roll
    short8 sa0_0, sa0_1, sa0_2, sa0_3, sa0_4, sa0_5;
    short8 sa1_0, sa1_1, sa1_2, sa1_3, sa1_4, sa1_5;
    short8 sa2_0, sa2_1, sa2_2, sa2_3, sa2_4, sa2_5;
    short8 sa3_0, sa3_1, sa3_2, sa3_3, sa3_4, sa3_5;
    LOADSTG(0, 0) LOADSTG(1, 1) LOADSTG(2, 2) LOADSTG(3, 3)

    RND(0,0)  RND(1,1)  RND(2,2)  RND(3,3)
    RND(4,0)  RND(5,1)  RND(6,2)  RND(7,3)
    RND(8,0)  RND(9,1)  RND(10,2) RND(11,3)

    __syncthreads();   // all sm_h / sm_x reads of this step done

    // ---- write x[t+1]
    if (t < TSTEPS-1){
      uint2 pk;
      pk.x = (unsigned)f2bf(xf0[0]) | ((unsigned)f2bf(xf0[1]) << 16);
      pk.y = (unsigned)f2bf(xf0[2]) | ((unsigned)f2bf(xf0[3]) << 16);
      *(uint2*)(sm_x + xr*256 + ((xc4*8) ^ ((xr & 7) << 4))) = pk;
      int r2 = 16 + xr;
      pk.x = (unsigned)f2bf(xf1[0]) | ((unsigned)f2bf(xf1[1]) << 16);
      pk.y = (unsigned)f2bf(xf1[2]) | ((unsigned)f2bf(xf1[3]) << 16);
      *(uint2*)(sm_x + r2*256 + ((xc4*8) ^ ((r2 & 7) << 4))) = pk;
    }

    // ---- lane-local gate math; write h_new (bf16, swizzled, 8B packed)
    #pragma unroll
    for (int cf = 0; cf < 2; ++cf){
      #pragma unroll
      for (int rf = 0; rf < 2; ++rf){
        int row = 16*rf + lo;
        unsigned q[4];
        #pragma unroll
        for (int j = 0; j < 4; ++j){
          float r  = sigm(ar[cf][rf][j]);
          float z  = sigm(az[cf][rf][j]);
          float n  = tanh_f(anx[cf][rf][j] + r*anh[cf][rf][j]);
          float hv = (1.f - z)*n + z*hold[cf][rf][j];
          hold[cf][rf][j] = hv;
          q[j] = f2bf(hv);
        }
        uint2 pk; pk.x = q[0] | (q[1] << 16); pk.y = q[2] | (q[3] << 16);
        int cbyte = (32*wv + 16*cf + 4*hi) * 2;
        *(uint2*)(sm_h + row*512 + (cbyte ^ ((row & 7) << 4))) = pk;
      }
    }
    __syncthreads();   // h[t+1], x[t+1] visible
  }

  // ---- epilogue: leaky(h_last) -> sm_h (bf16)
  #pragma unroll
  for (int cf = 0; cf < 2; ++cf){
    #pragma unroll
    for (int rf = 0; rf < 2; ++rf){
      int row = 16*rf + lo;
      unsigned q[4];
      #pragma unroll
      for (int j = 0; j < 4; ++j){
        float v = hold[cf][rf][j];
        v = (v >= 0.f) ? v : 0.01f*v;
        q[j] = f2bf(v);
      }
      uint2 pk; pk.x = q[0] | (q[1] << 16); pk.y = q[2] | (q[3] << 16);
      int cbyte = (32*wv + 16*cf + 4*hi) * 2;
      *(uint2*)(sm_h + row*512 + (cbyte ^ ((row & 7) << 4))) = pk;
    }
  }
  __syncthreads();

  // ---- heads: 8 waves = 2 heads x 4 out-frags; each wave does both row-frags
  const int head = wv >> 2;            // 0 = pi, 1 = vf
  const int mfo  = wv & 3;             // out-col frag
  const float* wh = head ? w_vf : w_pi;
  const float* bh = head ? b_vf : b_pi;
  floatx4 acc0 = {0.f,0.f,0.f,0.f}, acc1 = {0.f,0.f,0.f,0.f};
  #pragma unroll
  for (int kf = 0; kf < 8; ++kf){
    const float* ap = wh + (size_t)(16*mfo + lo)*HDIM + 32*kf + 8*hi;
    floatx4 av0 = *(const floatx4*)ap;
    floatx4 av1 = *(const floatx4*)(ap + 4);
    short8 a;
    a[0]=(short)f2bf(av0[0]); a[1]=(short)f2bf(av0[1]); a[2]=(short)f2bf(av0[2]); a[3]=(short)f2bf(av0[3]);
    a[4]=(short)f2bf(av1[0]); a[5]=(short)f2bf(av1[1]); a[6]=(short)f2bf(av1[2]); a[7]=(short)f2bf(av1[3]);
    short8 b0 = ldsH(sm_h, lo,      kf*64 + hi*16);
    short8 b1 = ldsH(sm_h, 16 + lo, kf*64 + hi*16);
    acc0 = MFMA(a, b0, acc0);
    acc1 = MFMA(a, b1, acc1);
  }
  const size_t outoff = (size_t)head * ((size_t)BATCH * ODIM);
  #pragma unroll
  for (int b = 0; b < 2; ++b){
    floatx4 ac = b ? acc1 : acc0;
    int grow = row0 + 16*b + lo;
    #pragma unroll
    for (int j = 0; j < 4; ++j){
      int od = 16*mfo + 4*hi + j;
      float v = ac[j] + bh[od];
      v = (v >= 0.f) ? v : 0.01f*v;
      out[outoff + (size_t)grow*ODIM + od] = v;
    }
  }
}

extern "C" void kernel_launch(void* const* d_in, const int* in_sizes, int n_in,
                              void* d_out, int out_size, void* d_ws, size_t ws_size,
                              hipStream_t stream){
  const float* feat = (const float*)d_in[0];
  const float* w_ih = (const float*)d_in[1];
  const float* w_hh = (const float*)d_in[2];
  const float* b_ih = (const float*)d_in[3];
  const float* b_hh = (const float*)d_in[4];
  const float* w_pi = (const float*)d_in[5];
  const float* b_pi = (const float*)d_in[6];
  const float* w_vf = (const float*)d_in[7];
  const float* b_vf = (const float*)d_in[8];

  unsigned short* warr = (unsigned short*)d_ws;   // 589824 B

  prep_weights<<<144, 256, 0, stream>>>(w_ih, w_hh, warr);
  gru_fused<<<NBLK, NTHR, 0, stream>>>(feat, warr, b_ih, b_hh,
                                       w_pi, b_pi, w_vf, b_vf, (float*)d_out);
}

// Round 14
// 877.869 us; speedup vs baseline: 1.6711x; 1.0762x over previous
//
#include <hip/hip_runtime.h>

#define BATCH  4096
#define TSTEPS 64
#define FDIM   128
#define HDIM   256
#define ODIM   64
#define MROWS  32
#define NBLK   128    // BATCH / MROWS
#define NTHR   1024   // 16 waves

#define WARR_BYTES 589824          // 48*12*64*8 bf16
#define NGRP  8
#define GRPSZ 16                   // NBLK / NGRP

typedef __attribute__((ext_vector_type(8))) short  short8;
typedef __attribute__((ext_vector_type(4))) float  floatx4;

#define MFMA(a,b,c) __builtin_amdgcn_mfma_f32_16x16x32_bf16((a),(b),(c),0,0,0)

__device__ __forceinline__ unsigned short f2bf(float f){
  unsigned u = __builtin_bit_cast(unsigned, f);
  u += 0x7FFFu + ((u >> 16) & 1u);           // RTNE
  return (unsigned short)(u >> 16);
}
__device__ __forceinline__ float sigm(float x){
  return __builtin_amdgcn_rcpf(1.f + __expf(-x));
}
__device__ __forceinline__ float tanh_f(float x){
  return 2.f * __builtin_amdgcn_rcpf(1.f + __expf(-2.f * x)) - 1.f;
}

// ---------------- phase 0: fragment weights + zero pacing counters ----------
// warr[((gf*12 + kf)*64 + lane)*8 + i]; gf 0..47, kf 0..7 = w_hh, 8..11 = w_ih
// element = W[16*gf + (lane&15)][32*kf + 8*(lane>>4) + i]  (A-frag, row=lane&15)
__global__ void prep_weights(const float* __restrict__ w_ih,
                             const float* __restrict__ w_hh,
                             unsigned short* __restrict__ warr,
                             unsigned* __restrict__ ctr){
  int idx = blockIdx.x * 256 + threadIdx.x;
  if (idx < 48*12*64){
    int gf   = idx / 768;
    int rr   = idx - gf*768;
    int kf   = rr >> 6;
    int lane = rr & 63;
    int lo = lane & 15, hi = lane >> 4;
    const float* src = (kf < 8) ? (w_hh + (size_t)(16*gf + lo)*HDIM + 32*kf     + 8*hi)
                                : (w_ih + (size_t)(16*gf + lo)*FDIM + 32*(kf-8) + 8*hi);
    unsigned short* dst = warr + (size_t)idx * 8;
    #pragma unroll
    for (int i = 0; i < 8; ++i) dst[i] = f2bf(src[i]);
  } else if (idx < 48*12*64 + 256){
    ctr[idx - 48*12*64] = 0u;        // zero pacing counters every launch (replay-safe)
  }
}

// ---- LDS swizzle (bank-quad = (col>>4) ^ (row&7); conflict-minimal)
__device__ __forceinline__ short8 ldsH(const unsigned char* sm, int row, int col){
  return *(const short8*)(sm + row*512 + (col ^ ((row & 7) << 4)));
}
__device__ __forceinline__ short8 ldsX(const unsigned char* sm, int row, int col){
  return *(const short8*)(sm + row*256 + (col ^ ((row & 7) << 4)));
}

// ---------------- main fused kernel ----------------
__global__ __launch_bounds__(NTHR, 4)
void gru_fused(const float* __restrict__ feat, const unsigned short* __restrict__ warr,
               const float* __restrict__ b_ih, const float* __restrict__ b_hh,
               const float* __restrict__ w_pi, const float* __restrict__ b_pi,
               const float* __restrict__ w_vf, const float* __restrict__ b_vf,
               unsigned* __restrict__ ctr,
               float* __restrict__ out){
  __shared__ __align__(16) unsigned char sm_h[MROWS*512];   // 16 KB bf16 [32][256] swizzled
  __shared__ __align__(16) unsigned char sm_x[MROWS*256];   // 8 KB  bf16 [32][128] swizzled
  __shared__ __align__(16) float biasL[1024];               // 4 KB bias tables

  const int tid  = threadIdx.x;
  const int wv   = tid >> 6;              // 0..15 -> owns h-cols [16wv, 16wv+16)
  const int lane = tid & 63;
  const int lo   = lane & 15, hi = lane >> 4;
  const int row0 = blockIdx.x * MROWS;
  const int cb   = 16*wv + 4*hi;          // gate/h col base for this lane
  const int gfr  = wv, gfz = 16 + wv, gfn = 32 + wv;
  const int grp  = blockIdx.x & (NGRP-1); // XCD round-robin heuristic grouping

  unsigned* grpCtr = ctr + grp*16;        // one cache line per group
  unsigned* topCtr = ctr + NGRP*16;       // release counter

  const unsigned short* wl = warr + lane*8;

  // ---- one-time: bias -> LDS
  if      (tid < 512) biasL[tid] = b_ih[tid] + b_hh[tid];   // r,z combined
  else if (tid < 768) biasL[tid] = b_ih[tid];               // xn
  else                biasL[tid] = b_hh[tid - 256];         // hn

  // ---- zero sm_h
  ((int4*)sm_h)[tid] = make_int4(0,0,0,0);
  // ---- stage x[0]
  {
    int r  = tid >> 5;
    int c4 = tid & 31;
    floatx4 v = __builtin_nontemporal_load(
        (const floatx4*)(feat + (size_t)(row0 + r)*(TSTEPS*FDIM)) + c4);
    uint2 pk;
    pk.x = (unsigned)f2bf(v[0]) | ((unsigned)f2bf(v[1]) << 16);
    pk.y = (unsigned)f2bf(v[2]) | ((unsigned)f2bf(v[3]) << 16);
    *(uint2*)(sm_x + r*256 + ((c4*8) ^ ((r & 7) << 4))) = pk;
  }

  float hold[2][4];
  #pragma unroll
  for (int m = 0; m < 2; ++m)
    #pragma unroll
    for (int j = 0; j < 4; ++j) hold[m][j] = 0.f;

  __syncthreads();

  const int xr  = tid >> 5;
  const int xc4 = tid & 31;

  #pragma unroll 1
  for (int t = 0; t < TSTEPS; ++t){
    // ---- prefetch x[t+1]
    int tn = (t < TSTEPS-1) ? (t+1) : (TSTEPS-1);
    floatx4 xf = __builtin_nontemporal_load(
        (const floatx4*)(feat + (size_t)(row0 + xr)*(TSTEPS*FDIM) + (size_t)tn*FDIM) + xc4);

    // ---- acc init from LDS bias
    floatx4 ar[2], az[2], anh[2], anx[2];
    {
      floatx4 vr = *(const floatx4*)(biasL + cb);
      floatx4 vz = *(const floatx4*)(biasL + 256 + cb);
      floatx4 vx = *(const floatx4*)(biasL + 512 + cb);
      floatx4 vh = *(const floatx4*)(biasL + 768 + cb);
      #pragma unroll
      for (int m = 0; m < 2; ++m){ ar[m] = vr; az[m] = vz; anh[m] = vh; anx[m] = vx; }
    }

    // ---- 12 K-rounds, rolling depth-1 A prefetch (R7-proven)
    short8 a0c = *(const short8*)(wl + (gfr*12 + 0)*512);
    short8 a1c = *(const short8*)(wl + (gfz*12 + 0)*512);
    short8 a2c = *(const short8*)(wl + (gfn*12 + 0)*512);
    #pragma unroll
    for (int g = 0; g < 12; ++g){
      short8 a0n, a1n, a2n;
      if (g < 11){
        a0n = *(const short8*)(wl + (gfr*12 + g + 1)*512);
        a1n = *(const short8*)(wl + (gfz*12 + g + 1)*512);
        a2n = *(const short8*)(wl + (gfn*12 + g + 1)*512);
      }
      #pragma unroll
      for (int m = 0; m < 2; ++m){
        short8 b = (g < 8) ? ldsH(sm_h, 16*m + lo, g*64 + hi*16)
                           : ldsX(sm_x, 16*m + lo, (g-8)*64 + hi*16);
        ar[m] = MFMA(a0c, b, ar[m]);
        az[m] = MFMA(a1c, b, az[m]);
        if (g < 8) anh[m] = MFMA(a2c, b, anh[m]);
        else       anx[m] = MFMA(a2c, b, anx[m]);
      }
      a0c = a0n; a1c = a1n; a2c = a2n;
    }
    __syncthreads();   // all sm_h / sm_x reads of this step done

    // ---- pacing barrier: arrive (lane 0 only; overlaps with gate math below)
    if (tid == 0){
      unsigned old = atomicAdd(grpCtr, 1u);
      if ((old & (GRPSZ-1u)) == GRPSZ-1u) atomicAdd(topCtr, 1u);
    }

    // ---- write x[t+1]
    if (t < TSTEPS-1){
      uint2 pk;
      pk.x = (unsigned)f2bf(xf[0]) | ((unsigned)f2bf(xf[1]) << 16);
      pk.y = (unsigned)f2bf(xf[2]) | ((unsigned)f2bf(xf[3]) << 16);
      *(uint2*)(sm_x + xr*256 + ((xc4*8) ^ ((xr & 7) << 4))) = pk;
    }

    // ---- lane-local gate math; write h_new (bf16, swizzled, 8B packed)
    #pragma unroll
    for (int m = 0; m < 2; ++m){
      int row = 16*m + lo;
      unsigned q[4];
      #pragma unroll
      for (int j = 0; j < 4; ++j){
        float r  = sigm(ar[m][j]);
        float z  = sigm(az[m][j]);
        float n  = tanh_f(anx[m][j] + r*anh[m][j]);
        float hv = (1.f - z)*n + z*hold[m][j];
        hold[m][j] = hv;
        q[j] = f2bf(hv);
      }
      uint2 pk; pk.x = q[0] | (q[1] << 16); pk.y = q[2] | (q[3] << 16);
      *(uint2*)(sm_h + row*512 + ((cb*2) ^ ((row & 7) << 4))) = pk;
    }

    // ---- pacing barrier: wait for all 8 groups (lane 0 spins; others block on sync)
    if (tid == 0){
      unsigned target = (unsigned)(NGRP * (t + 1));
      while (__hip_atomic_load(topCtr, __ATOMIC_RELAXED, __HIP_MEMORY_SCOPE_AGENT) < target)
        __builtin_amdgcn_s_sleep(2);
    }
    __syncthreads();   // h[t+1], x[t+1] visible; block released in phase
  }

  // ---- epilogue: leaky(h_last) -> sm_h (bf16)
  #pragma unroll
  for (int m = 0; m < 2; ++m){
    int row = 16*m + lo;
    unsigned q[4];
    #pragma unroll
    for (int j = 0; j < 4; ++j){
      float v = hold[m][j];
      v = (v >= 0.f) ? v : 0.01f*v;
      q[j] = f2bf(v);
    }
    uint2 pk; pk.x = q[0] | (q[1] << 16); pk.y = q[2] | (q[3] << 16);
    *(uint2*)(sm_h + row*512 + ((cb*2) ^ ((row & 7) << 4))) = pk;
  }
  __syncthreads();

  // ---- heads: 16 waves = 2 heads x 4 out-frags x 2 row-frags
  const int head = wv >> 3;
  const int mfo  = (wv >> 1) & 3;
  const int rh   = wv & 1;
  const float* wh = head ? w_vf : w_pi;
  const float* bh = head ? b_vf : b_pi;
  floatx4 acc = {0.f,0.f,0.f,0.f};
  #pragma unroll
  for (int kf = 0; kf < 8; ++kf){
    const float* ap = wh + (size_t)(16*mfo + lo)*HDIM + 32*kf + 8*hi;
    floatx4 av0 = *(const floatx4*)ap;
    floatx4 av1 = *(const floatx4*)(ap + 4);
    short8 a;
    a[0]=(short)f2bf(av0[0]); a[1]=(short)f2bf(av0[1]); a[2]=(short)f2bf(av0[2]); a[3]=(short)f2bf(av0[3]);
    a[4]=(short)f2bf(av1[0]); a[5]=(short)f2bf(av1[1]); a[6]=(short)f2bf(av1[2]); a[7]=(short)f2bf(av1[3]);
    short8 b = ldsH(sm_h, 16*rh + lo, kf*64 + hi*16);
    acc = MFMA(a, b, acc);
  }
  const size_t outoff = (size_t)head * ((size_t)BATCH * ODIM);
  {
    int grow = row0 + 16*rh + lo;
    #pragma unroll
    for (int j = 0; j < 4; ++j){
      int od = 16*mfo + 4*hi + j;
      float v = acc[j] + bh[od];
      v = (v >= 0.f) ? v : 0.01f*v;
      out[outoff + (size_t)grow*ODIM + od] = v;
    }
  }
}

extern "C" void kernel_launch(void* const* d_in, const int* in_sizes, int n_in,
                              void* d_out, int out_size, void* d_ws, size_t ws_size,
                              hipStream_t stream){
  const float* feat = (const float*)d_in[0];
  const float* w_ih = (const float*)d_in[1];
  const float* w_hh = (const float*)d_in[2];
  const float* b_ih = (const float*)d_in[3];
  const float* b_hh = (const float*)d_in[4];
  const float* w_pi = (const float*)d_in[5];
  const float* b_pi = (const float*)d_in[6];
  const float* w_vf = (const float*)d_in[7];
  const float* b_vf = (const float*)d_in[8];

  unsigned short* warr = (unsigned short*)d_ws;             // 589824 B
  unsigned* ctr = (unsigned*)((char*)d_ws + WARR_BYTES);    // 256 uints (zeroed by prep)

  prep_weights<<<145, 256, 0, stream>>>(w_ih, w_hh, warr, ctr);
  gru_fused<<<NBLK, NTHR, 0, stream>>>(feat, warr, b_ih, b_hh,
                                       w_pi, b_pi, w_vf, b_vf, ctr, (float*)d_out);
}

// Round 15
// 820.635 us; speedup vs baseline: 1.7877x; 1.0697x over previous
//
#include <hip/hip_runtime.h>

#define BATCH  4096
#define TSTEPS 64
#define FDIM   128
#define HDIM   256
#define ODIM   64
#define MROWS  32
#define NBLK   128    // BATCH / MROWS
#define NTHR   1024   // 16 waves, 4 waves/SIMD

#define WARR_BYTES 589824
#define XG_BYTES   402653184ull     // 4096*64*768 bf16
#define SMEM_XG    163840           // sm_h 16K + wlds 144K (full 160K LDS)

typedef __attribute__((ext_vector_type(8))) short    short8;
typedef __attribute__((ext_vector_type(4))) float    floatx4;
typedef __attribute__((ext_vector_type(4))) unsigned uintx4;

#define MFMA(a,b,c) __builtin_amdgcn_mfma_f32_16x16x32_bf16((a),(b),(c),0,0,0)

__device__ __forceinline__ unsigned short f2bf(float f){
  unsigned u = __builtin_bit_cast(unsigned, f);
  u += 0x7FFFu + ((u >> 16) & 1u);           // RTNE
  return (unsigned short)(u >> 16);
}
__device__ __forceinline__ float bf2f(unsigned us){
  return __builtin_bit_cast(float, us << 16);
}
__device__ __forceinline__ float sigm(float x){
  return __builtin_amdgcn_rcpf(1.f + __expf(-x));
}
__device__ __forceinline__ float tanh_f(float x){
  return 2.f * __builtin_amdgcn_rcpf(1.f + __expf(-2.f * x)) - 1.f;
}
__device__ __forceinline__ short8 cvt8(floatx4 a, floatx4 b){
  union { unsigned u[4]; short8 s; } r;
  r.u[0] = (unsigned)f2bf(a[0]) | ((unsigned)f2bf(a[1]) << 16);
  r.u[1] = (unsigned)f2bf(a[2]) | ((unsigned)f2bf(a[3]) << 16);
  r.u[2] = (unsigned)f2bf(b[0]) | ((unsigned)f2bf(b[1]) << 16);
  r.u[3] = (unsigned)f2bf(b[2]) | ((unsigned)f2bf(b[3]) << 16);
  return r.s;
}

// ---------------- phase 0: fragment weights into d_ws ----------
// warr[((gf*12 + kf)*64 + lane)*8 + i]; gf 0..47, kf 0..7 = w_hh, 8..11 = w_ih
// element = W[16*gf + (lane&15)][32*kf + 8*(lane>>4) + i]  (A-frag, row=lane&15)
__global__ void prep_weights(const float* __restrict__ w_ih,
                             const float* __restrict__ w_hh,
                             unsigned short* __restrict__ warr){
  int idx = blockIdx.x * 256 + threadIdx.x;
  if (idx >= 48*12*64) return;
  int gf   = idx / 768;
  int rr   = idx - gf*768;
  int kf   = rr >> 6;
  int lane = rr & 63;
  int lo = lane & 15, hi = lane >> 4;
  const float* src = (kf < 8) ? (w_hh + (size_t)(16*gf + lo)*HDIM + 32*kf     + 8*hi)
                              : (w_ih + (size_t)(16*gf + lo)*FDIM + 32*(kf-8) + 8*hi);
  unsigned short* dst = warr + (size_t)idx * 8;
  #pragma unroll
  for (int i = 0; i < 8; ++i) dst[i] = f2bf(src[i]);
}

// ---- LDS swizzle (bank-quad = (col>>4) ^ (row&7); conflict-minimal)
__device__ __forceinline__ short8 ldsH(const unsigned char* sm, int row, int col){
  return *(const short8*)(sm + row*512 + (col ^ ((row & 7) << 4)));
}
__device__ __forceinline__ short8 ldsX(const unsigned char* sm, int row, int col){
  return *(const short8*)(sm + row*256 + (col ^ ((row & 7) << 4)));
}

// ---------------- phase A: xg = feat @ w_ih^T + b_ih  (time-parallel) --------
// layout: int4-plane per (blk,t,wv,g): xg4[(((blk*64+t)*16+wv)*3+g)*64 + lane]
//   = {m0 j01, m0 j23, m1 j01, m1 j23} bf16 pairs; cols = 16wv+4hi+j (+g*256)
__global__ __launch_bounds__(NTHR, 4)
void xg_pass(const float* __restrict__ feat, const unsigned short* __restrict__ warr,
             const float* __restrict__ b_ih, uintx4* __restrict__ xg4){
  const int tid  = threadIdx.x;
  const int wv   = tid >> 6;
  const int lane = tid & 63;
  const int lo   = lane & 15, hi = lane >> 4;
  const int row0 = blockIdx.x * MROWS;
  const int cb   = 16*wv + 4*hi;

  const unsigned short* wl = warr + lane*8;
  const int gfs[3] = {wv, 16 + wv, 32 + wv};

  // A-frags (w_ih, kf 8..11) loaded once: 12 short8
  short8 wa[3][4];
  #pragma unroll
  for (int g = 0; g < 3; ++g)
    #pragma unroll
    for (int kx = 0; kx < 4; ++kx)
      wa[g][kx] = *(const short8*)(wl + (gfs[g]*12 + 8 + kx)*512);

  floatx4 bi[3];
  bi[0] = *(const floatx4*)(b_ih + cb);
  bi[1] = *(const floatx4*)(b_ih + 256 + cb);
  bi[2] = *(const floatx4*)(b_ih + 512 + cb);

  #pragma unroll 1
  for (int t = 0; t < TSTEPS; ++t){
    floatx4 acc[3][2];
    #pragma unroll
    for (int g = 0; g < 3; ++g){ acc[g][0] = bi[g]; acc[g][1] = bi[g]; }

    #pragma unroll
    for (int kx = 0; kx < 4; ++kx){
      #pragma unroll
      for (int m = 0; m < 2; ++m){
        const float* xp = feat + (size_t)(row0 + 16*m + lo)*(TSTEPS*FDIM)
                               + (size_t)t*FDIM + 32*kx + 8*hi;
        short8 b = cvt8(*(const floatx4*)xp, *(const floatx4*)(xp + 4));
        #pragma unroll
        for (int g = 0; g < 3; ++g) acc[g][m] = MFMA(wa[g][kx], b, acc[g][m]);
      }
    }
    const size_t pb = (((size_t)blockIdx.x*TSTEPS + t)*16 + wv)*192 + lane;
    #pragma unroll
    for (int g = 0; g < 3; ++g){
      uintx4 v;
      v[0] = (unsigned)f2bf(acc[g][0][0]) | ((unsigned)f2bf(acc[g][0][1]) << 16);
      v[1] = (unsigned)f2bf(acc[g][0][2]) | ((unsigned)f2bf(acc[g][0][3]) << 16);
      v[2] = (unsigned)f2bf(acc[g][1][0]) | ((unsigned)f2bf(acc[g][1][1]) << 16);
      v[3] = (unsigned)f2bf(acc[g][1][2]) | ((unsigned)f2bf(acc[g][1][3]) << 16);
      __builtin_nontemporal_store(v, xg4 + pb + g*64);
    }
  }
}

// ---------------- phase B (primary): recurrent loop, w_ih gone ---------------
__global__ __launch_bounds__(NTHR, 4)
void gru_xg(const unsigned short* __restrict__ warr, const uintx4* __restrict__ xg4,
            const float* __restrict__ b_hh,
            const float* __restrict__ w_pi, const float* __restrict__ b_pi,
            const float* __restrict__ w_vf, const float* __restrict__ b_vf,
            float* __restrict__ out){
  extern __shared__ __align__(16) unsigned char smem[];
  unsigned char* sm_h = smem;             // 16 KB bf16 [32][256] swizzled
  unsigned char* wlds = smem + 16384;     // 144 KB: frag(gf, kf 0..2) at ((gf*3+kf)*64+ln)*16

  const int tid  = threadIdx.x;
  const int wv   = tid >> 6;
  const int lane = tid & 63;
  const int lo   = lane & 15, hi = lane >> 4;
  const int row0 = blockIdx.x * MROWS;
  const int cb   = 16*wv + 4*hi;
  const int gfr  = wv, gfz = 16 + wv, gfn = 32 + wv;

  const unsigned short* wl = warr + lane*8;

  floatx4 vrh = *(const floatx4*)(b_hh + cb);
  floatx4 vzh = *(const floatx4*)(b_hh + 256 + cb);
  floatx4 vnh = *(const floatx4*)(b_hh + 512 + cb);

  // preload wlds (kf 0..2 of all 48 gf): 9216 int4, 9/thread
  #pragma unroll
  for (int i = 0; i < 9; ++i){
    int idx = tid + i*NTHR;
    int gfk = idx >> 6, ln = idx & 63;
    int gf  = gfk / 3,  kf = gfk - gf*3;
    ((int4*)wlds)[idx] = ((const int4*)warr)[(gf*12 + kf)*64 + ln];
  }
  ((int4*)sm_h)[tid] = make_int4(0,0,0,0);

  float hold[2][4] = {};
  __syncthreads();

  #pragma unroll 1
  for (int t = 0; t < TSTEPS; ++t){
    // xg prefetch (consumed after the barrier, in gate math)
    const size_t pb = (((size_t)blockIdx.x*TSTEPS + t)*16 + wv)*192 + lane;
    uintx4 xgr = __builtin_nontemporal_load(xg4 + pb);
    uintx4 xgz = __builtin_nontemporal_load(xg4 + pb + 64);
    uintx4 xgn = __builtin_nontemporal_load(xg4 + pb + 128);

    floatx4 ar[2], az[2], anh[2];
    ar[0]=vrh; ar[1]=vrh; az[0]=vzh; az[1]=vzh; anh[0]=vnh; anh[1]=vnh;

    // prologue stream: kf3 frags
    short8 a0c = *(const short8*)(wl + (gfr*12 + 3)*512);
    short8 a1c = *(const short8*)(wl + (gfz*12 + 3)*512);
    short8 a2c = *(const short8*)(wl + (gfn*12 + 3)*512);

    // rounds kf 0..2: A from wlds
    #pragma unroll
    for (int kf = 0; kf < 3; ++kf){
      short8 a0 = *(const short8*)(wlds + ((gfr*3 + kf)*64 + lane)*16);
      short8 a1 = *(const short8*)(wlds + ((gfz*3 + kf)*64 + lane)*16);
      short8 a2 = *(const short8*)(wlds + ((gfn*3 + kf)*64 + lane)*16);
      #pragma unroll
      for (int m = 0; m < 2; ++m){
        short8 b = ldsH(sm_h, 16*m + lo, kf*64 + hi*16);
        ar[m]  = MFMA(a0, b, ar[m]);
        az[m]  = MFMA(a1, b, az[m]);
        anh[m] = MFMA(a2, b, anh[m]);
      }
    }
    // rounds kf 3..7: rolling depth-1 stream
    #pragma unroll
    for (int g = 3; g < 8; ++g){
      short8 a0n, a1n, a2n;
      if (g < 7){
        a0n = *(const short8*)(wl + (gfr*12 + g + 1)*512);
        a1n = *(const short8*)(wl + (gfz*12 + g + 1)*512);
        a2n = *(const short8*)(wl + (gfn*12 + g + 1)*512);
      }
      #pragma unroll
      for (int m = 0; m < 2; ++m){
        short8 b = ldsH(sm_h, 16*m + lo, g*64 + hi*16);
        ar[m]  = MFMA(a0c, b, ar[m]);
        az[m]  = MFMA(a1c, b, az[m]);
        anh[m] = MFMA(a2c, b, anh[m]);
      }
      a0c = a0n; a1c = a1n; a2c = a2n;
    }
    __syncthreads();   // all sm_h reads of this step done

    // gate math: xg (bf16) + MFMA h-part
    #pragma unroll
    for (int m = 0; m < 2; ++m){
      int row = 16*m + lo;
      unsigned q[4];
      #pragma unroll
      for (int j = 0; j < 4; ++j){
        unsigned wr = xgr[m*2 + (j >> 1)], wz = xgz[m*2 + (j >> 1)], wn = xgn[m*2 + (j >> 1)];
        unsigned sh = (j & 1) * 16;
        float xr = bf2f((wr >> sh) & 0xffffu);
        float xz = bf2f((wz >> sh) & 0xffffu);
        float xn = bf2f((wn >> sh) & 0xffffu);
        float r  = sigm(ar[m][j] + xr);
        float z  = sigm(az[m][j] + xz);
        float n  = tanh_f(xn + r*anh[m][j]);
        float hv = (1.f - z)*n + z*hold[m][j];
        hold[m][j] = hv;
        q[j] = f2bf(hv);
      }
      uint2 pk; pk.x = q[0] | (q[1] << 16); pk.y = q[2] | (q[3] << 16);
      *(uint2*)(sm_h + row*512 + ((cb*2) ^ ((row & 7) << 4))) = pk;
    }
    __syncthreads();   // h[t+1] visible
  }

  // ---- epilogue: leaky(h_last) -> sm_h
  #pragma unroll
  for (int m = 0; m < 2; ++m){
    int row = 16*m + lo;
    unsigned q[4];
    #pragma unroll
    for (int j = 0; j < 4; ++j){
      float v = hold[m][j];
      v = (v >= 0.f) ? v : 0.01f*v;
      q[j] = f2bf(v);
    }
    uint2 pk; pk.x = q[0] | (q[1] << 16); pk.y = q[2] | (q[3] << 16);
    *(uint2*)(sm_h + row*512 + ((cb*2) ^ ((row & 7) << 4))) = pk;
  }
  __syncthreads();

  // ---- heads
  const int head = wv >> 3;
  const int mfo  = (wv >> 1) & 3;
  const int rh   = wv & 1;
  const float* wh = head ? w_vf : w_pi;
  const float* bh = head ? b_vf : b_pi;
  floatx4 acc = {0.f,0.f,0.f,0.f};
  #pragma unroll
  for (int kf = 0; kf < 8; ++kf){
    const float* ap = wh + (size_t)(16*mfo + lo)*HDIM + 32*kf + 8*hi;
    short8 a = cvt8(*(const floatx4*)ap, *(const floatx4*)(ap + 4));
    short8 b = ldsH(sm_h, 16*rh + lo, kf*64 + hi*16);
    acc = MFMA(a, b, acc);
  }
  const size_t outoff = (size_t)head * ((size_t)BATCH * ODIM);
  {
    int grow = row0 + 16*rh + lo;
    #pragma unroll
    for (int j = 0; j < 4; ++j){
      int od = 16*mfo + 4*hi + j;
      float v = acc[j] + bh[od];
      v = (v >= 0.f) ? v : 0.01f*v;
      out[outoff + (size_t)grow*ODIM + od] = v;
    }
  }
}

// ---------------- fallback: proven R14-minus-pacing (direct stream) ----------
__global__ __launch_bounds__(NTHR, 4)
void gru_fb(const float* __restrict__ feat, const unsigned short* __restrict__ warr,
            const float* __restrict__ b_ih, const float* __restrict__ b_hh,
            const float* __restrict__ w_pi, const float* __restrict__ b_pi,
            const float* __restrict__ w_vf, const float* __restrict__ b_vf,
            float* __restrict__ out){
  __shared__ __align__(16) unsigned char sm_h[MROWS*512];
  __shared__ __align__(16) unsigned char sm_x[MROWS*256];
  __shared__ __align__(16) float biasL[1024];

  const int tid  = threadIdx.x;
  const int wv   = tid >> 6;
  const int lane = tid & 63;
  const int lo   = lane & 15, hi = lane >> 4;
  const int row0 = blockIdx.x * MROWS;
  const int cb   = 16*wv + 4*hi;
  const int gfr  = wv, gfz = 16 + wv, gfn = 32 + wv;

  const unsigned short* wl = warr + lane*8;

  if      (tid < 512) biasL[tid] = b_ih[tid] + b_hh[tid];
  else if (tid < 768) biasL[tid] = b_ih[tid];
  else                biasL[tid] = b_hh[tid - 256];

  ((int4*)sm_h)[tid] = make_int4(0,0,0,0);
  {
    int r  = tid >> 5;
    int c4 = tid & 31;
    floatx4 v = __builtin_nontemporal_load(
        (const floatx4*)(feat + (size_t)(row0 + r)*(TSTEPS*FDIM)) + c4);
    uint2 pk;
    pk.x = (unsigned)f2bf(v[0]) | ((unsigned)f2bf(v[1]) << 16);
    pk.y = (unsigned)f2bf(v[2]) | ((unsigned)f2bf(v[3]) << 16);
    *(uint2*)(sm_x + r*256 + ((c4*8) ^ ((r & 7) << 4))) = pk;
  }

  float hold[2][4] = {};
  __syncthreads();

  const int xr  = tid >> 5;
  const int xc4 = tid & 31;

  #pragma unroll 1
  for (int t = 0; t < TSTEPS; ++t){
    int tn = (t < TSTEPS-1) ? (t+1) : (TSTEPS-1);
    floatx4 xf = __builtin_nontemporal_load(
        (const floatx4*)(feat + (size_t)(row0 + xr)*(TSTEPS*FDIM) + (size_t)tn*FDIM) + xc4);

    floatx4 ar[2], az[2], anh[2], anx[2];
    {
      floatx4 vr = *(const floatx4*)(biasL + cb);
      floatx4 vz = *(const floatx4*)(biasL + 256 + cb);
      floatx4 vx = *(const floatx4*)(biasL + 512 + cb);
      floatx4 vh = *(const floatx4*)(biasL + 768 + cb);
      #pragma unroll
      for (int m = 0; m < 2; ++m){ ar[m] = vr; az[m] = vz; anh[m] = vh; anx[m] = vx; }
    }

    short8 a0c = *(const short8*)(wl + (gfr*12 + 0)*512);
    short8 a1c = *(const short8*)(wl + (gfz*12 + 0)*512);
    short8 a2c = *(const short8*)(wl + (gfn*12 + 0)*512);
    #pragma unroll
    for (int g = 0; g < 12; ++g){
      short8 a0n, a1n, a2n;
      if (g < 11){
        a0n = *(const short8*)(wl + (gfr*12 + g + 1)*512);
        a1n = *(const short8*)(wl + (gfz*12 + g + 1)*512);
        a2n = *(const short8*)(wl + (gfn*12 + g + 1)*512);
      }
      #pragma unroll
      for (int m = 0; m < 2; ++m){
        short8 b = (g < 8) ? ldsH(sm_h, 16*m + lo, g*64 + hi*16)
                           : ldsX(sm_x, 16*m + lo, (g-8)*64 + hi*16);
        ar[m] = MFMA(a0c, b, ar[m]);
        az[m] = MFMA(a1c, b, az[m]);
        if (g < 8) anh[m] = MFMA(a2c, b, anh[m]);
        else       anx[m] = MFMA(a2c, b, anx[m]);
      }
      a0c = a0n; a1c = a1n; a2c = a2n;
    }
    __syncthreads();

    if (t < TSTEPS-1){
      uint2 pk;
      pk.x = (unsigned)f2bf(xf[0]) | ((unsigned)f2bf(xf[1]) << 16);
      pk.y = (unsigned)f2bf(xf[2]) | ((unsigned)f2bf(xf[3]) << 16);
      *(uint2*)(sm_x + xr*256 + ((xc4*8) ^ ((xr & 7) << 4))) = pk;
    }

    #pragma unroll
    for (int m = 0; m < 2; ++m){
      int row = 16*m + lo;
      unsigned q[4];
      #pragma unroll
      for (int j = 0; j < 4; ++j){
        float r  = sigm(ar[m][j]);
        float z  = sigm(az[m][j]);
        float n  = tanh_f(anx[m][j] + r*anh[m][j]);
        float hv = (1.f - z)*n + z*hold[m][j];
        hold[m][j] = hv;
        q[j] = f2bf(hv);
      }
      uint2 pk; pk.x = q[0] | (q[1] << 16); pk.y = q[2] | (q[3] << 16);
      *(uint2*)(sm_h + row*512 + ((cb*2) ^ ((row & 7) << 4))) = pk;
    }
    __syncthreads();
  }

  #pragma unroll
  for (int m = 0; m < 2; ++m){
    int row = 16*m + lo;
    unsigned q[4];
    #pragma unroll
    for (int j = 0; j < 4; ++j){
      float v = hold[m][j];
      v = (v >= 0.f) ? v : 0.01f*v;
      q[j] = f2bf(v);
    }
    uint2 pk; pk.x = q[0] | (q[1] << 16); pk.y = q[2] | (q[3] << 16);
    *(uint2*)(sm_h + row*512 + ((cb*2) ^ ((row & 7) << 4))) = pk;
  }
  __syncthreads();

  const int head = wv >> 3;
  const int mfo  = (wv >> 1) & 3;
  const int rh   = wv & 1;
  const float* wh = head ? w_vf : w_pi;
  const float* bh = head ? b_vf : b_pi;
  floatx4 acc = {0.f,0.f,0.f,0.f};
  #pragma unroll
  for (int kf = 0; kf < 8; ++kf){
    const float* ap = wh + (size_t)(16*mfo + lo)*HDIM + 32*kf + 8*hi;
    short8 a = cvt8(*(const floatx4*)ap, *(const floatx4*)(ap + 4));
    short8 b = ldsH(sm_h, 16*rh + lo, kf*64 + hi*16);
    acc = MFMA(a, b, acc);
  }
  const size_t outoff = (size_t)head * ((size_t)BATCH * ODIM);
  {
    int grow = row0 + 16*rh + lo;
    #pragma unroll
    for (int j = 0; j < 4; ++j){
      int od = 16*mfo + 4*hi + j;
      float v = acc[j] + bh[od];
      v = (v >= 0.f) ? v : 0.01f*v;
      out[outoff + (size_t)grow*ODIM + od] = v;
    }
  }
}

extern "C" void kernel_launch(void* const* d_in, const int* in_sizes, int n_in,
                              void* d_out, int out_size, void* d_ws, size_t ws_size,
                              hipStream_t stream){
  const float* feat = (const float*)d_in[0];
  const float* w_ih = (const float*)d_in[1];
  const float* w_hh = (const float*)d_in[2];
  const float* b_ih = (const float*)d_in[3];
  const float* b_hh = (const float*)d_in[4];
  const float* w_pi = (const float*)d_in[5];
  const float* b_pi = (const float*)d_in[6];
  const float* w_vf = (const float*)d_in[7];
  const float* b_vf = (const float*)d_in[8];

  unsigned short* warr = (unsigned short*)d_ws;

  prep_weights<<<144, 256, 0, stream>>>(w_ih, w_hh, warr);

  if (ws_size >= WARR_BYTES + XG_BYTES){
    uintx4* xg4 = (uintx4*)((char*)d_ws + WARR_BYTES);
    xg_pass<<<NBLK, NTHR, 0, stream>>>(feat, warr, b_ih, xg4);
    hipFuncSetAttribute((const void*)gru_xg,
                        hipFuncAttributeMaxDynamicSharedMemorySize, SMEM_XG);
    gru_xg<<<NBLK, NTHR, SMEM_XG, stream>>>(warr, xg4, b_hh,
                                            w_pi, b_pi, w_vf, b_vf, (float*)d_out);
  } else {
    gru_fb<<<NBLK, NTHR, 0, stream>>>(feat, warr, b_ih, b_hh,
                                      w_pi, b_pi, w_vf, b_vf, (float*)d_out);
  }
}

// Round 16
// 494.386 us; speedup vs baseline: 2.9674x; 1.6599x over previous
//
#include <hip/hip_runtime.h>

#define BATCH  4096
#define TSTEPS 64
#define FDIM   128
#define HDIM   256
#define ODIM   64
#define MROWS  32
#define NBLK   128    // BATCH / MROWS
#define NTHR   1024   // 16 waves, 4 waves/SIMD

#define XGBLK  512    // xg_pass: 4 t-groups x 128 row-groups
#define TG     16     // timesteps per xg block

#define WARR_BYTES 589824
#define XG_BYTES   402653184ull     // 4096*64*768 bf16
#define SMEM_XG    163840           // gru_xg: sm_h 16K + wlds 144K

typedef __attribute__((ext_vector_type(8))) short    short8;
typedef __attribute__((ext_vector_type(4))) float    floatx4;
typedef __attribute__((ext_vector_type(4))) unsigned uintx4;

#define MFMA(a,b,c) __builtin_amdgcn_mfma_f32_16x16x32_bf16((a),(b),(c),0,0,0)

__device__ __forceinline__ unsigned short f2bf(float f){
  unsigned u = __builtin_bit_cast(unsigned, f);
  u += 0x7FFFu + ((u >> 16) & 1u);           // RTNE
  return (unsigned short)(u >> 16);
}
__device__ __forceinline__ float bf2f(unsigned us){
  return __builtin_bit_cast(float, us << 16);
}
__device__ __forceinline__ float sigm(float x){
  return __builtin_amdgcn_rcpf(1.f + __expf(-x));
}
__device__ __forceinline__ float tanh_f(float x){
  return 2.f * __builtin_amdgcn_rcpf(1.f + __expf(-2.f * x)) - 1.f;
}
__device__ __forceinline__ short8 cvt8(floatx4 a, floatx4 b){
  union { unsigned u[4]; short8 s; } r;
  r.u[0] = (unsigned)f2bf(a[0]) | ((unsigned)f2bf(a[1]) << 16);
  r.u[1] = (unsigned)f2bf(a[2]) | ((unsigned)f2bf(a[3]) << 16);
  r.u[2] = (unsigned)f2bf(b[0]) | ((unsigned)f2bf(b[1]) << 16);
  r.u[3] = (unsigned)f2bf(b[2]) | ((unsigned)f2bf(b[3]) << 16);
  return r.s;
}

// ---------------- phase 0: fragment weights into d_ws ----------
// warr[((gf*12 + kf)*64 + lane)*8 + i]; gf 0..47, kf 0..7 = w_hh, 8..11 = w_ih
// element = W[16*gf + (lane&15)][32*kf + 8*(lane>>4) + i]  (A-frag, row=lane&15)
__global__ void prep_weights(const float* __restrict__ w_ih,
                             const float* __restrict__ w_hh,
                             unsigned short* __restrict__ warr){
  int idx = blockIdx.x * 256 + threadIdx.x;
  if (idx >= 48*12*64) return;
  int gf   = idx / 768;
  int rr   = idx - gf*768;
  int kf   = rr >> 6;
  int lane = rr & 63;
  int lo = lane & 15, hi = lane >> 4;
  const float* src = (kf < 8) ? (w_hh + (size_t)(16*gf + lo)*HDIM + 32*kf     + 8*hi)
                              : (w_ih + (size_t)(16*gf + lo)*FDIM + 32*(kf-8) + 8*hi);
  unsigned short* dst = warr + (size_t)idx * 8;
  #pragma unroll
  for (int i = 0; i < 8; ++i) dst[i] = f2bf(src[i]);
}

// ---- LDS swizzle (bank-quad = (col>>4) ^ (row&7); conflict-minimal)
__device__ __forceinline__ short8 ldsH(const unsigned char* sm, int row, int col){
  return *(const short8*)(sm + row*512 + (col ^ ((row & 7) << 4)));
}
__device__ __forceinline__ short8 ldsX(const unsigned char* sm, int row, int col){
  return *(const short8*)(sm + row*256 + (col ^ ((row & 7) << 4)));
}

// ---------------- phase A: xg = feat @ w_ih^T (NO bias; added in phase B) ----
// layout: int4-plane per (rg,t,wv,g): xg4[(((rg*64+t)*16+wv)*3+g)*64 + lane]
//   = {m0 j01, m0 j23, m1 j01, m1 j23} bf16 pairs; cols = 16wv+4hi+j (+g*256)
__global__ __launch_bounds__(NTHR, 4)
void xg_pass(const float* __restrict__ feat, const unsigned short* __restrict__ warr,
             uintx4* __restrict__ xg4){
  __shared__ __align__(16) unsigned char sm_x[2][MROWS*256];   // 2 x 8 KB swizzled

  const int tid  = threadIdx.x;
  const int wv   = tid >> 6;
  const int lane = tid & 63;
  const int lo   = lane & 15, hi = lane >> 4;
  const int rg   = blockIdx.x & 127;        // row group 0..127
  const int tg   = blockIdx.x >> 7;         // t group 0..3
  const int row0 = rg * MROWS;
  const int t0   = tg * TG;

  const unsigned short* wl = warr + lane*8;
  const int gfs[3] = {wv, 16 + wv, 32 + wv};

  // A-frags (w_ih, kf 8..11) loaded once: 12 short8 = 48 VGPR
  short8 wa[3][4];
  #pragma unroll
  for (int g = 0; g < 3; ++g)
    #pragma unroll
    for (int kx = 0; kx < 4; ++kx)
      wa[g][kx] = *(const short8*)(wl + (gfs[g]*12 + 8 + kx)*512);

  const int xr  = tid >> 5;     // staging: row + float4-chunk, 1 per thread
  const int xc4 = tid & 31;

  // stage x[t0]
  {
    floatx4 v = __builtin_nontemporal_load(
        (const floatx4*)(feat + (size_t)(row0 + xr)*(TSTEPS*FDIM) + (size_t)t0*FDIM) + xc4);
    uint2 pk;
    pk.x = (unsigned)f2bf(v[0]) | ((unsigned)f2bf(v[1]) << 16);
    pk.y = (unsigned)f2bf(v[2]) | ((unsigned)f2bf(v[3]) << 16);
    *(uint2*)(sm_x[0] + xr*256 + ((xc4*8) ^ ((xr & 7) << 4))) = pk;
  }
  __syncthreads();

  #pragma unroll 1
  for (int tt = 0; tt < TG; ++tt){
    const int t   = t0 + tt;
    const int cur = tt & 1, nxt = cur ^ 1;

    // prefetch x[t+1] (coalesced; written after mid barrier)
    floatx4 xf;
    if (tt + 1 < TG)
      xf = __builtin_nontemporal_load(
          (const floatx4*)(feat + (size_t)(row0 + xr)*(TSTEPS*FDIM) + (size_t)(t+1)*FDIM) + xc4);

    floatx4 acc[3][2];
    #pragma unroll
    for (int g = 0; g < 3; ++g){
      acc[g][0] = (floatx4){0.f,0.f,0.f,0.f};
      acc[g][1] = (floatx4){0.f,0.f,0.f,0.f};
    }

    #pragma unroll
    for (int kx = 0; kx < 4; ++kx){
      short8 b0 = ldsX(sm_x[cur], lo,      kx*64 + hi*16);
      short8 b1 = ldsX(sm_x[cur], 16 + lo, kx*64 + hi*16);
      #pragma unroll
      for (int g = 0; g < 3; ++g){
        acc[g][0] = MFMA(wa[g][kx], b0, acc[g][0]);
        acc[g][1] = MFMA(wa[g][kx], b1, acc[g][1]);
      }
    }

    // store 3 int4 planes (nontemporal)
    const size_t pb = (((size_t)rg*TSTEPS + t)*16 + wv)*192 + lane;
    #pragma unroll
    for (int g = 0; g < 3; ++g){
      uintx4 v;
      v[0] = (unsigned)f2bf(acc[g][0][0]) | ((unsigned)f2bf(acc[g][0][1]) << 16);
      v[1] = (unsigned)f2bf(acc[g][0][2]) | ((unsigned)f2bf(acc[g][0][3]) << 16);
      v[2] = (unsigned)f2bf(acc[g][1][0]) | ((unsigned)f2bf(acc[g][1][1]) << 16);
      v[3] = (unsigned)f2bf(acc[g][1][2]) | ((unsigned)f2bf(acc[g][1][3]) << 16);
      __builtin_nontemporal_store(v, xg4 + pb + g*64);
    }

    __syncthreads();   // all reads of sm_x[cur] done (and prior reads of nxt)
    if (tt + 1 < TG){
      uint2 pk;
      pk.x = (unsigned)f2bf(xf[0]) | ((unsigned)f2bf(xf[1]) << 16);
      pk.y = (unsigned)f2bf(xf[2]) | ((unsigned)f2bf(xf[3]) << 16);
      *(uint2*)(sm_x[nxt] + xr*256 + ((xc4*8) ^ ((xr & 7) << 4))) = pk;
    }
    __syncthreads();   // x[t+1] visible
  }
}

// ---------------- phase B (primary): recurrent loop, w_ih gone ---------------
__global__ __launch_bounds__(NTHR, 4)
void gru_xg(const unsigned short* __restrict__ warr, const uintx4* __restrict__ xg4,
            const float* __restrict__ b_ih, const float* __restrict__ b_hh,
            const float* __restrict__ w_pi, const float* __restrict__ b_pi,
            const float* __restrict__ w_vf, const float* __restrict__ b_vf,
            float* __restrict__ out){
  extern __shared__ __align__(16) unsigned char smem[];
  unsigned char* sm_h = smem;             // 16 KB bf16 [32][256] swizzled
  unsigned char* wlds = smem + 16384;     // 144 KB: frag(gf, kf 0..2) at ((gf*3+kf)*64+ln)*16

  const int tid  = threadIdx.x;
  const int wv   = tid >> 6;
  const int lane = tid & 63;
  const int lo   = lane & 15, hi = lane >> 4;
  const int row0 = blockIdx.x * MROWS;
  const int cb   = 16*wv + 4*hi;
  const int gfr  = wv, gfz = 16 + wv, gfn = 32 + wv;

  const unsigned short* wl = warr + lane*8;

  // combined biases (b_ih now folded here, not in xg)
  floatx4 vrh = *(const floatx4*)(b_ih + cb)       + *(const floatx4*)(b_hh + cb);
  floatx4 vzh = *(const floatx4*)(b_ih + 256 + cb) + *(const floatx4*)(b_hh + 256 + cb);
  floatx4 vnh = *(const floatx4*)(b_hh + 512 + cb);
  floatx4 vnx = *(const floatx4*)(b_ih + 512 + cb);

  // preload wlds (kf 0..2 of all 48 gf): 9216 int4, 9/thread
  #pragma unroll
  for (int i = 0; i < 9; ++i){
    int idx = tid + i*NTHR;
    int gfk = idx >> 6, ln = idx & 63;
    int gf  = gfk / 3,  kf = gfk - gf*3;
    ((int4*)wlds)[idx] = ((const int4*)warr)[(gf*12 + kf)*64 + ln];
  }
  ((int4*)sm_h)[tid] = make_int4(0,0,0,0);

  float hold[2][4] = {};
  __syncthreads();

  #pragma unroll 1
  for (int t = 0; t < TSTEPS; ++t){
    // xg prefetch (consumed after the barrier, in gate math)
    const size_t pb = (((size_t)blockIdx.x*TSTEPS + t)*16 + wv)*192 + lane;
    uintx4 xgr = __builtin_nontemporal_load(xg4 + pb);
    uintx4 xgz = __builtin_nontemporal_load(xg4 + pb + 64);
    uintx4 xgn = __builtin_nontemporal_load(xg4 + pb + 128);

    floatx4 ar[2], az[2], anh[2];
    ar[0]=vrh; ar[1]=vrh; az[0]=vzh; az[1]=vzh; anh[0]=vnh; anh[1]=vnh;

    // prologue stream: kf3 frags
    short8 a0c = *(const short8*)(wl + (gfr*12 + 3)*512);
    short8 a1c = *(const short8*)(wl + (gfz*12 + 3)*512);
    short8 a2c = *(const short8*)(wl + (gfn*12 + 3)*512);

    // rounds kf 0..2: A from wlds
    #pragma unroll
    for (int kf = 0; kf < 3; ++kf){
      short8 a0 = *(const short8*)(wlds + ((gfr*3 + kf)*64 + lane)*16);
      short8 a1 = *(const short8*)(wlds + ((gfz*3 + kf)*64 + lane)*16);
      short8 a2 = *(const short8*)(wlds + ((gfn*3 + kf)*64 + lane)*16);
      #pragma unroll
      for (int m = 0; m < 2; ++m){
        short8 b = ldsH(sm_h, 16*m + lo, kf*64 + hi*16);
        ar[m]  = MFMA(a0, b, ar[m]);
        az[m]  = MFMA(a1, b, az[m]);
        anh[m] = MFMA(a2, b, anh[m]);
      }
    }
    // rounds kf 3..7: rolling depth-1 stream
    #pragma unroll
    for (int g = 3; g < 8; ++g){
      short8 a0n, a1n, a2n;
      if (g < 7){
        a0n = *(const short8*)(wl + (gfr*12 + g + 1)*512);
        a1n = *(const short8*)(wl + (gfz*12 + g + 1)*512);
        a2n = *(const short8*)(wl + (gfn*12 + g + 1)*512);
      }
      #pragma unroll
      for (int m = 0; m < 2; ++m){
        short8 b = ldsH(sm_h, 16*m + lo, g*64 + hi*16);
        ar[m]  = MFMA(a0c, b, ar[m]);
        az[m]  = MFMA(a1c, b, az[m]);
        anh[m] = MFMA(a2c, b, anh[m]);
      }
      a0c = a0n; a1c = a1n; a2c = a2n;
    }
    __syncthreads();   // all sm_h reads of this step done

    // gate math: xg (bf16, biasless) + biases + MFMA h-part
    #pragma unroll
    for (int m = 0; m < 2; ++m){
      int row = 16*m + lo;
      unsigned q[4];
      #pragma unroll
      for (int j = 0; j < 4; ++j){
        unsigned wr = xgr[m*2 + (j >> 1)], wz = xgz[m*2 + (j >> 1)], wn = xgn[m*2 + (j >> 1)];
        unsigned sh = (j & 1) * 16;
        float xr = bf2f((wr >> sh) & 0xffffu);
        float xz = bf2f((wz >> sh) & 0xffffu);
        float xn = bf2f((wn >> sh) & 0xffffu);
        float r  = sigm(ar[m][j] + xr);
        float z  = sigm(az[m][j] + xz);
        float n  = tanh_f(xn + vnx[j] + r*anh[m][j]);
        float hv = (1.f - z)*n + z*hold[m][j];
        hold[m][j] = hv;
        q[j] = f2bf(hv);
      }
      uint2 pk; pk.x = q[0] | (q[1] << 16); pk.y = q[2] | (q[3] << 16);
      *(uint2*)(sm_h + row*512 + ((cb*2) ^ ((row & 7) << 4))) = pk;
    }
    __syncthreads();   // h[t+1] visible
  }

  // ---- epilogue: leaky(h_last) -> sm_h
  #pragma unroll
  for (int m = 0; m < 2; ++m){
    int row = 16*m + lo;
    unsigned q[4];
    #pragma unroll
    for (int j = 0; j < 4; ++j){
      float v = hold[m][j];
      v = (v >= 0.f) ? v : 0.01f*v;
      q[j] = f2bf(v);
    }
    uint2 pk; pk.x = q[0] | (q[1] << 16); pk.y = q[2] | (q[3] << 16);
    *(uint2*)(sm_h + row*512 + ((cb*2) ^ ((row & 7) << 4))) = pk;
  }
  __syncthreads();

  // ---- heads
  const int head = wv >> 3;
  const int mfo  = (wv >> 1) & 3;
  const int rh   = wv & 1;
  const float* wh = head ? w_vf : w_pi;
  const float* bh = head ? b_vf : b_pi;
  floatx4 acc = {0.f,0.f,0.f,0.f};
  #pragma unroll
  for (int kf = 0; kf < 8; ++kf){
    const float* ap = wh + (size_t)(16*mfo + lo)*HDIM + 32*kf + 8*hi;
    short8 a = cvt8(*(const floatx4*)ap, *(const floatx4*)(ap + 4));
    short8 b = ldsH(sm_h, 16*rh + lo, kf*64 + hi*16);
    acc = MFMA(a, b, acc);
  }
  const size_t outoff = (size_t)head * ((size_t)BATCH * ODIM);
  {
    int grow = row0 + 16*rh + lo;
    #pragma unroll
    for (int j = 0; j < 4; ++j){
      int od = 16*mfo + 4*hi + j;
      float v = acc[j] + bh[od];
      v = (v >= 0.f) ? v : 0.01f*v;
      out[outoff + (size_t)grow*ODIM + od] = v;
    }
  }
}

// ---------------- fallback: proven R14-minus-pacing (direct stream) ----------
__global__ __launch_bounds__(NTHR, 4)
void gru_fb(const float* __restrict__ feat, const unsigned short* __restrict__ warr,
            const float* __restrict__ b_ih, const float* __restrict__ b_hh,
            const float* __restrict__ w_pi, const float* __restrict__ b_pi,
            const float* __restrict__ w_vf, const float* __restrict__ b_vf,
            float* __restrict__ out){
  __shared__ __align__(16) unsigned char sm_h[MROWS*512];
  __shared__ __align__(16) unsigned char sm_x[MROWS*256];
  __shared__ __align__(16) float biasL[1024];

  const int tid  = threadIdx.x;
  const int wv   = tid >> 6;
  const int lane = tid & 63;
  const int lo   = lane & 15, hi = lane >> 4;
  const int row0 = blockIdx.x * MROWS;
  const int cb   = 16*wv + 4*hi;
  const int gfr  = wv, gfz = 16 + wv, gfn = 32 + wv;

  const unsigned short* wl = warr + lane*8;

  if      (tid < 512) biasL[tid] = b_ih[tid] + b_hh[tid];
  else if (tid < 768) biasL[tid] = b_ih[tid];
  else                biasL[tid] = b_hh[tid - 256];

  ((int4*)sm_h)[tid] = make_int4(0,0,0,0);
  {
    int r  = tid >> 5;
    int c4 = tid & 31;
    floatx4 v = __builtin_nontemporal_load(
        (const floatx4*)(feat + (size_t)(row0 + r)*(TSTEPS*FDIM)) + c4);
    uint2 pk;
    pk.x = (unsigned)f2bf(v[0]) | ((unsigned)f2bf(v[1]) << 16);
    pk.y = (unsigned)f2bf(v[2]) | ((unsigned)f2bf(v[3]) << 16);
    *(uint2*)(sm_x + r*256 + ((c4*8) ^ ((r & 7) << 4))) = pk;
  }

  float hold[2][4] = {};
  __syncthreads();

  const int xr  = tid >> 5;
  const int xc4 = tid & 31;

  #pragma unroll 1
  for (int t = 0; t < TSTEPS; ++t){
    int tn = (t < TSTEPS-1) ? (t+1) : (TSTEPS-1);
    floatx4 xf = __builtin_nontemporal_load(
        (const floatx4*)(feat + (size_t)(row0 + xr)*(TSTEPS*FDIM) + (size_t)tn*FDIM) + xc4);

    floatx4 ar[2], az[2], anh[2], anx[2];
    {
      floatx4 vr = *(const floatx4*)(biasL + cb);
      floatx4 vz = *(const floatx4*)(biasL + 256 + cb);
      floatx4 vx = *(const floatx4*)(biasL + 512 + cb);
      floatx4 vh = *(const floatx4*)(biasL + 768 + cb);
      #pragma unroll
      for (int m = 0; m < 2; ++m){ ar[m] = vr; az[m] = vz; anh[m] = vh; anx[m] = vx; }
    }

    short8 a0c = *(const short8*)(wl + (gfr*12 + 0)*512);
    short8 a1c = *(const short8*)(wl + (gfz*12 + 0)*512);
    short8 a2c = *(const short8*)(wl + (gfn*12 + 0)*512);
    #pragma unroll
    for (int g = 0; g < 12; ++g){
      short8 a0n, a1n, a2n;
      if (g < 11){
        a0n = *(const short8*)(wl + (gfr*12 + g + 1)*512);
        a1n = *(const short8*)(wl + (gfz*12 + g + 1)*512);
        a2n = *(const short8*)(wl + (gfn*12 + g + 1)*512);
      }
      #pragma unroll
      for (int m = 0; m < 2; ++m){
        short8 b = (g < 8) ? ldsH(sm_h, 16*m + lo, g*64 + hi*16)
                           : ldsX(sm_x, 16*m + lo, (g-8)*64 + hi*16);
        ar[m] = MFMA(a0c, b, ar[m]);
        az[m] = MFMA(a1c, b, az[m]);
        if (g < 8) anh[m] = MFMA(a2c, b, anh[m]);
        else       anx[m] = MFMA(a2c, b, anx[m]);
      }
      a0c = a0n; a1c = a1n; a2c = a2n;
    }
    __syncthreads();

    if (t < TSTEPS-1){
      uint2 pk;
      pk.x = (unsigned)f2bf(xf[0]) | ((unsigned)f2bf(xf[1]) << 16);
      pk.y = (unsigned)f2bf(xf[2]) | ((unsigned)f2bf(xf[3]) << 16);
      *(uint2*)(sm_x + xr*256 + ((xc4*8) ^ ((xr & 7) << 4))) = pk;
    }

    #pragma unroll
    for (int m = 0; m < 2; ++m){
      int row = 16*m + lo;
      unsigned q[4];
      #pragma unroll
      for (int j = 0; j < 4; ++j){
        float r  = sigm(ar[m][j]);
        float z  = sigm(az[m][j]);
        float n  = tanh_f(anx[m][j] + r*anh[m][j]);
        float hv = (1.f - z)*n + z*hold[m][j];
        hold[m][j] = hv;
        q[j] = f2bf(hv);
      }
      uint2 pk; pk.x = q[0] | (q[1] << 16); pk.y = q[2] | (q[3] << 16);
      *(uint2*)(sm_h + row*512 + ((cb*2) ^ ((row & 7) << 4))) = pk;
    }
    __syncthreads();
  }

  #pragma unroll
  for (int m = 0; m < 2; ++m){
    int row = 16*m + lo;
    unsigned q[4];
    #pragma unroll
    for (int j = 0; j < 4; ++j){
      float v = hold[m][j];
      v = (v >= 0.f) ? v : 0.01f*v;
      q[j] = f2bf(v);
    }
    uint2 pk; pk.x = q[0] | (q[1] << 16); pk.y = q[2] | (q[3] << 16);
    *(uint2*)(sm_h + row*512 + ((cb*2) ^ ((row & 7) << 4))) = pk;
  }
  __syncthreads();

  const int head = wv >> 3;
  const int mfo  = (wv >> 1) & 3;
  const int rh   = wv & 1;
  const float* wh = head ? w_vf : w_pi;
  const float* bh = head ? b_vf : b_pi;
  floatx4 acc = {0.f,0.f,0.f,0.f};
  #pragma unroll
  for (int kf = 0; kf < 8; ++kf){
    const float* ap = wh + (size_t)(16*mfo + lo)*HDIM + 32*kf + 8*hi;
    short8 a = cvt8(*(const floatx4*)ap, *(const floatx4*)(ap + 4));
    short8 b = ldsH(sm_h, 16*rh + lo, kf*64 + hi*16);
    acc = MFMA(a, b, acc);
  }
  const size_t outoff = (size_t)head * ((size_t)BATCH * ODIM);
  {
    int grow = row0 + 16*rh + lo;
    #pragma unroll
    for (int j = 0; j < 4; ++j){
      int od = 16*mfo + 4*hi + j;
      float v = acc[j] + bh[od];
      v = (v >= 0.f) ? v : 0.01f*v;
      out[outoff + (size_t)grow*ODIM + od] = v;
    }
  }
}

extern "C" void kernel_launch(void* const* d_in, const int* in_sizes, int n_in,
                              void* d_out, int out_size, void* d_ws, size_t ws_size,
                              hipStream_t stream){
  const float* feat = (const float*)d_in[0];
  const float* w_ih = (const float*)d_in[1];
  const float* w_hh = (const float*)d_in[2];
  const float* b_ih = (const float*)d_in[3];
  const float* b_hh = (const float*)d_in[4];
  const float* w_pi = (const float*)d_in[5];
  const float* b_pi = (const float*)d_in[6];
  const float* w_vf = (const float*)d_in[7];
  const float* b_vf = (const float*)d_in[8];

  unsigned short* warr = (unsigned short*)d_ws;

  prep_weights<<<144, 256, 0, stream>>>(w_ih, w_hh, warr);

  if (ws_size >= WARR_BYTES + XG_BYTES){
    uintx4* xg4 = (uintx4*)((char*)d_ws + WARR_BYTES);
    xg_pass<<<XGBLK, NTHR, 0, stream>>>(feat, warr, xg4);
    hipFuncSetAttribute((const void*)gru_xg,
                        hipFuncAttributeMaxDynamicSharedMemorySize, SMEM_XG);
    gru_xg<<<NBLK, NTHR, SMEM_XG, stream>>>(warr, xg4, b_ih, b_hh,
                                            w_pi, b_pi, w_vf, b_vf, (float*)d_out);
  } else {
    gru_fb<<<NBLK, NTHR, 0, stream>>>(feat, warr, b_ih, b_hh,
                                      w_pi, b_pi, w_vf, b_vf, (float*)d_out);
  }
}